// Round 1
// 2882.548 us; speedup vs baseline: 1.1120x; 1.1120x over previous
//
#include <hip/hip_runtime.h>
#include <hip/hip_bf16.h>

typedef unsigned short u16;
typedef unsigned int u32;
typedef __attribute__((ext_vector_type(8))) short bf8_t;  // 8 bf16 = 16B
typedef __attribute__((ext_vector_type(4))) float f4_t;

#define D 512
#define H 8
#define DK 64
#define NL 6
#define V 32000
#define FF 2048
#define B 8
#define S 128
#define NTOK (B * S)   // 1024

static __device__ inline u16 f2bs(float x) {
    __hip_bfloat16 h = __float2bfloat16(x);
    return *reinterpret_cast<u16*>(&h);
}
static __device__ inline float blo(u32 u) { return __uint_as_float(u << 16); }
static __device__ inline float bhi(u32 u) { return __uint_as_float(u & 0xffff0000u); }
static __device__ inline u32 pk2(float a, float b) {
    return ((u32)f2bs(b) << 16) | f2bs(a);
}

// ---------------------------------------------------------------------------
// Weight convert+transpose: in fp32 [R,C] -> out bf16 [C,R]   (z = matrix idx)
// ---------------------------------------------------------------------------
__global__ __launch_bounds__(256) void wconv_t(const float* __restrict__ in,
                                               u16* __restrict__ out,
                                               int R, int C)
{
    __shared__ u16 T[32][40];
    const float* inz = in + (size_t)blockIdx.z * R * C;
    u16* outz = out + (size_t)blockIdx.z * R * C;
    int r0 = blockIdx.y * 32, c0 = blockIdx.x * 32;
    int tid = threadIdx.x;
    {
        int r = tid >> 3, c4 = (tid & 7) * 4;
        float4 f = *(const float4*)&inz[(size_t)(r0 + r) * C + c0 + c4];
        T[c4 + 0][r] = f2bs(f.x);
        T[c4 + 1][r] = f2bs(f.y);
        T[c4 + 2][r] = f2bs(f.z);
        T[c4 + 3][r] = f2bs(f.w);
    }
    __syncthreads();
    {
        int c = tid >> 3, r4 = (tid & 7) * 4;
        u32 lo = ((u32)T[c][r4 + 1] << 16) | T[c][r4 + 0];
        u32 hi = ((u32)T[c][r4 + 3] << 16) | T[c][r4 + 2];
        uint2 p; p.x = lo; p.y = hi;
        *(uint2*)&outz[(size_t)(c0 + c) * R + r0 + r4] = p;
    }
}

// ---------------------------------------------------------------------------
// Both embeddings in one launch. blocks [0,1024) -> src/xe, [1024,2048) -> tgt/xd
// ---------------------------------------------------------------------------
__global__ __launch_bounds__(256) void embed2_kernel(
    const int* __restrict__ src, const int* __restrict__ tgt,
    const float* __restrict__ tok, const float* __restrict__ pos,
    float* __restrict__ xe, float* __restrict__ xd)
{
    int row = blockIdx.x;
    const int* ids; float* X; int r;
    if (row < NTOK) { ids = src; X = xe; r = row; }
    else            { ids = tgt; X = xd; r = row - NTOK; }
    int s  = r & (S - 1);
    int id = ids[r];
    int d  = threadIdx.x * 2;
    float2 t = *(const float2*)&tok[(size_t)id * D + d];
    float2 p = *(const float2*)&pos[(size_t)s * D + d];
    float2 o; o.x = t.x + p.x; o.y = t.y + p.y;
    *(float2*)&X[(size_t)r * D + d] = o;
}

// ---------------------------------------------------------------------------
// LayerNorm: fp32 in, bf16 out. One wave per row. (only for mem / final dec)
// ---------------------------------------------------------------------------
__global__ void ln_kernel(const float* __restrict__ X,
                          const float* __restrict__ g,
                          const float* __restrict__ bta,
                          u16* __restrict__ Y)
{
    int row  = blockIdx.x;
    int lane = threadIdx.x;          // 64
    float v[8];
    float sum = 0.f;
#pragma unroll
    for (int i = 0; i < 8; ++i) {
        v[i] = X[row * D + i * 64 + lane];
        sum += v[i];
    }
#pragma unroll
    for (int off = 32; off > 0; off >>= 1) sum += __shfl_xor(sum, off);
    float mu = sum * (1.f / D);
    float var = 0.f;
#pragma unroll
    for (int i = 0; i < 8; ++i) { float d = v[i] - mu; var += d * d; }
#pragma unroll
    for (int off = 32; off > 0; off >>= 1) var += __shfl_xor(var, off);
    var *= (1.f / D);
    float r = rsqrtf(var + 1e-6f);
#pragma unroll
    for (int i = 0; i < 8; ++i) {
        int d = i * 64 + lane;
        Y[row * D + d] = f2bs((v[i] - mu) * r * g[d] + bta[d]);
    }
}

// ---------------------------------------------------------------------------
// MFMA GEMM, NT: C = A[1024,K] @ Bt[z][N,K]^T + bias (+resid fp32) (+relu)
// KC=256 chunking: K=512 -> 2 latency exposures; K=2048 -> 8 (was 32).
// LDS: MT=32 -> 51KB (3 blocks/CU), MT=64 -> 68KB (2 blocks/CU).
// lnA: A is fp32 [1024,512]; per-row mean/rstd pre-pass (sum/sumsq), then
//      normalize+cast during A staging (fuses the LayerNorm kernel).
// bf32: B is fp32 [N,K] (generator reads tok_emb directly, no ec pass).
// swz:  flat-grid XCD-chunked mapping so the 16 row-blocks of one B col-tile
//       land on ONE XCD -> B fetched once per XCD L2.
// Row stride 264 shorts = 132 dwords == 4 (mod 32): proven 2-way-free pattern.
// ---------------------------------------------------------------------------
template<int MT>   // 32 (128 thr) or 64 (256 thr)
__global__ __launch_bounds__(MT * 4) void gk(
    const u16* __restrict__ Abf, const float* __restrict__ Axf,
    const float* __restrict__ g, const float* __restrict__ be,
    const void* __restrict__ Btv, const float* __restrict__ bias,
    const float* __restrict__ resid, void* __restrict__ Cout,
    int K, int N, int relu, int obf, int lnA, int bf32, int swz,
    long wzs, long bzs, long ozs)
{
    constexpr int THREADS = MT * 4;
    __shared__ __align__(16) u16 As[MT][264];
    __shared__ __align__(16) u16 Bs[64][264];
    __shared__ float muS[MT], rsS[MT];

    int tid = threadIdx.x;
    int col0, row0, z;
    if (swz) {
        // generator: 8064 flat blocks; id%8 pins XCD; col tile c = q*8+s so a
        // col-tile's 16 row-blocks share an XCD; c in [500,504) are dummies.
        int id = blockIdx.x;
        int s = id & 7, t = id >> 3;
        int r = t & 15, q = t >> 4;
        int c = q * 8 + s;
        if (c >= 500) return;
        col0 = c * 64; row0 = r * MT; z = 0;
    } else {
        col0 = blockIdx.x * 64; row0 = blockIdx.y * MT; z = blockIdx.z;
    }

    const float* bz = bias ? bias + (size_t)z * bzs : nullptr;

    int wv  = tid >> 6, ln = tid & 63;
    int m16 = ln & 15, quad = ln >> 4;

    if (lnA) {
        // 4 threads/row stats pre-pass (K==512 on this path)
        int r = tid >> 2, s4 = tid & 3;
        const float* xr = Axf + (size_t)(row0 + r) * D;
        float sum = 0.f, ss = 0.f;
#pragma unroll
        for (int c = 0; c < 32; ++c) {
            float4 f = *(const float4*)&xr[c * 16 + s4 * 4];
            sum += f.x + f.y + f.z + f.w;
            ss  += f.x * f.x + f.y * f.y + f.z * f.z + f.w * f.w;
        }
        sum += __shfl_xor(sum, 1); sum += __shfl_xor(sum, 2);
        ss  += __shfl_xor(ss, 1);  ss  += __shfl_xor(ss, 2);
        if (s4 == 0) {
            float mu  = sum * (1.f / D);
            float var = ss * (1.f / D) - mu * mu;
            muS[r] = mu;
            rsS[r] = rsqrtf(var + 1e-6f);
        }
        __syncthreads();
    }

    f4_t acc[4];
#pragma unroll
    for (int j = 0; j < 4; ++j) acc[j] = (f4_t){0.f, 0.f, 0.f, 0.f};

    for (int kc = 0; kc < K; kc += 256) {
        // ---- stage A chunk [MT][256] ----
        if (lnA) {
#pragma unroll
            for (int i = tid; i < MT * 32; i += THREADS) {
                int m = i >> 5, k8 = (i & 31) * 8;
                const float* sp = &Axf[(size_t)(row0 + m) * D + kc + k8];
                float4 f0 = *(const float4*)sp;
                float4 f1 = *(const float4*)(sp + 4);
                float4 g0 = *(const float4*)&g[kc + k8];
                float4 g1 = *(const float4*)&g[kc + k8 + 4];
                float4 b0 = *(const float4*)&be[kc + k8];
                float4 b1 = *(const float4*)&be[kc + k8 + 4];
                float mu = muS[m], rs = rsS[m];
                uint4 o;
                o.x = pk2((f0.x - mu) * rs * g0.x + b0.x, (f0.y - mu) * rs * g0.y + b0.y);
                o.y = pk2((f0.z - mu) * rs * g0.z + b0.z, (f0.w - mu) * rs * g0.w + b0.w);
                o.z = pk2((f1.x - mu) * rs * g1.x + b1.x, (f1.y - mu) * rs * g1.y + b1.y);
                o.w = pk2((f1.z - mu) * rs * g1.z + b1.z, (f1.w - mu) * rs * g1.w + b1.w);
                *(uint4*)&As[m][k8] = o;
            }
        } else {
#pragma unroll
            for (int i = tid; i < MT * 32; i += THREADS) {
                int m = i >> 5, k8 = (i & 31) * 8;
                *(bf8_t*)&As[m][k8] = *(const bf8_t*)&Abf[(size_t)(row0 + m) * K + kc + k8];
            }
        }
        // ---- stage B chunk [64][256] ----
        if (bf32) {
            const float* Bf = (const float*)Btv + (size_t)z * wzs;
#pragma unroll
            for (int i = tid; i < 64 * 32; i += THREADS) {
                int n = i >> 5, k8 = (i & 31) * 8;
                const float* sp = &Bf[(size_t)(col0 + n) * K + kc + k8];
                float4 f0 = *(const float4*)sp;
                float4 f1 = *(const float4*)(sp + 4);
                uint4 o;
                o.x = pk2(f0.x, f0.y); o.y = pk2(f0.z, f0.w);
                o.z = pk2(f1.x, f1.y); o.w = pk2(f1.z, f1.w);
                *(uint4*)&Bs[n][k8] = o;
            }
        } else {
            const u16* Bz = (const u16*)Btv + (size_t)z * wzs;
#pragma unroll
            for (int i = tid; i < 64 * 32; i += THREADS) {
                int n = i >> 5, k8 = (i & 31) * 8;
                *(bf8_t*)&Bs[n][k8] = *(const bf8_t*)&Bz[(size_t)(col0 + n) * K + kc + k8];
            }
        }
        __syncthreads();

#pragma unroll
        for (int ks = 0; ks < 8; ++ks) {
            bf8_t a = *(const bf8_t*)&As[wv * 16 + m16][ks * 32 + quad * 8];
#pragma unroll
            for (int j = 0; j < 4; ++j) {
                bf8_t b = *(const bf8_t*)&Bs[j * 16 + m16][ks * 32 + quad * 8];
                acc[j] = __builtin_amdgcn_mfma_f32_16x16x32_bf16(a, b, acc[j], 0, 0, 0);
            }
        }
        __syncthreads();
    }

#pragma unroll
    for (int j = 0; j < 4; ++j) {
        int col = col0 + j * 16 + m16;
        float bv = bz ? bz[col] : 0.f;
#pragma unroll
        for (int r = 0; r < 4; ++r) {
            int row = row0 + wv * 16 + quad * 4 + r;
            float val = acc[j][r] + bv;
            if (resid) val += resid[(size_t)row * N + col];
            if (relu) val = fmaxf(val, 0.f);
            if (obf) ((u16*)Cout + (size_t)z * ozs)[(size_t)row * N + col] = f2bs(val);
            else     ((float*)Cout + (size_t)z * ozs)[(size_t)row * N + col] = val;
        }
    }
}

// ---------------------------------------------------------------------------
// Attention, bf16 I/O. Block = (qc,h,b), 256 thr = 4 waves, wave owns 8 q-rows.
// ---------------------------------------------------------------------------
__global__ __launch_bounds__(256) void attn_kernel(
    const u16* __restrict__ Qb, const u16* __restrict__ Kb,
    const u16* __restrict__ Vb, u16* __restrict__ Ob,
    const int* __restrict__ mask_ids, int causal)
{
    __shared__ u16 Ks[128][66];
    __shared__ u32 Vp[128][36];
    __shared__ u16 Qs[32][66];
    __shared__ float es[4][132];

    int qc = blockIdx.x;
    int h  = blockIdx.y;
    int b  = blockIdx.z;
    int tid = threadIdx.x;

    for (int i = tid; i < 1024; i += 256) {
        int t = i >> 3, d8 = (i & 7) * 8;
        size_t src = (size_t)(b * S + t) * D + h * DK + d8;
        uint4 kv = *(const uint4*)&Kb[src];
        *(u32*)&Ks[t][d8 + 0] = kv.x;
        *(u32*)&Ks[t][d8 + 2] = kv.y;
        *(u32*)&Ks[t][d8 + 4] = kv.z;
        *(u32*)&Ks[t][d8 + 6] = kv.w;
        uint4 vv = *(const uint4*)&Vb[src];
        *(uint4*)&Vp[t][d8 >> 1] = vv;
    }
    {
        int m = tid >> 3, d8 = (tid & 7) * 8;
        uint4 qv = *(const uint4*)&Qb[(size_t)(b * S + qc * 32 + m) * D + h * DK + d8];
        *(u32*)&Qs[m][d8 + 0] = qv.x;
        *(u32*)&Qs[m][d8 + 2] = qv.y;
        *(u32*)&Qs[m][d8 + 4] = qv.z;
        *(u32*)&Qs[m][d8 + 6] = qv.w;
    }
    __syncthreads();

    int w      = tid >> 6;
    int lane   = tid & 63;
    int d2     = lane & 31;
    int th     = lane >> 5;
    bool pad0  = (mask_ids[b * S + lane] == 1);
    bool pad1  = (mask_ids[b * S + 64 + lane] == 1);

    for (int qi = 0; qi < 8; ++qi) {
        int qloc = w * 8 + qi;
        int qpos = qc * 32 + qloc;

        float s0 = 0.f, s1 = 0.f;
#pragma unroll
        for (int i = 0; i < 32; ++i) {
            u32 qu = *(const u32*)&Qs[qloc][2 * i];
            u32 k0 = *(const u32*)&Ks[lane][2 * i];
            u32 k1 = *(const u32*)&Ks[lane + 64][2 * i];
            float ql = blo(qu), qh = bhi(qu);
            s0 += ql * blo(k0) + qh * bhi(k0);
            s1 += ql * blo(k1) + qh * bhi(k1);
        }
        s0 *= 0.125f; s1 *= 0.125f;
        if (pad0 || (causal && lane > qpos))        s0 = -1e30f;
        if (pad1 || (causal && (lane + 64) > qpos)) s1 = -1e30f;

        float mx = fmaxf(s0, s1);
#pragma unroll
        for (int off = 32; off > 0; off >>= 1) mx = fmaxf(mx, __shfl_xor(mx, off));
        float e0 = __expf(s0 - mx), e1 = __expf(s1 - mx);
        float l = e0 + e1;
#pragma unroll
        for (int off = 32; off > 0; off >>= 1) l += __shfl_xor(l, off);
        float inv = 1.f / l;
        es[w][lane]      = e0 * inv;
        es[w][lane + 64] = e1 * inv;

        float o0 = 0.f, o1 = 0.f;
#pragma unroll 8
        for (int i = 0; i < 64; ++i) {
            int t = th * 64 + i;
            float e = es[w][t];
            u32 vu = Vp[t][d2];
            o0 += e * blo(vu);
            o1 += e * bhi(vu);
        }
        o0 += __shfl_xor(o0, 32);
        o1 += __shfl_xor(o1, 32);
        if (th == 0) {
            u32 packed = ((u32)f2bs(o1) << 16) | f2bs(o0);
            *(u32*)&Ob[(size_t)(b * S + qpos) * D + h * DK + 2 * d2] = packed;
        }
    }
}

// ---------------------------------------------------------------------------
// Fused log-softmax: one block per row, 125 elements/thread held in registers.
// Single read + single write of the 131MB logits (replaces lse + lsub).
// ---------------------------------------------------------------------------
__global__ __launch_bounds__(256) void lsm_kernel(float* __restrict__ out)
{
    __shared__ float red[8];
    int row = blockIdx.x, tid = threadIdx.x;
    float* rp = out + (size_t)row * V;
    float v[125];
    float m = -1e30f;
#pragma unroll
    for (int i = 0; i < 125; ++i) {
        v[i] = rp[i * 256 + tid];
        m = fmaxf(m, v[i]);
    }
#pragma unroll
    for (int off = 32; off > 0; off >>= 1) m = fmaxf(m, __shfl_xor(m, off));
    int wv = tid >> 6;
    if ((tid & 63) == 0) red[wv] = m;
    __syncthreads();
    m = fmaxf(fmaxf(red[0], red[1]), fmaxf(red[2], red[3]));
    float l = 0.f;
#pragma unroll
    for (int i = 0; i < 125; ++i) l += __expf(v[i] - m);
#pragma unroll
    for (int off = 32; off > 0; off >>= 1) l += __shfl_xor(l, off);
    if ((tid & 63) == 0) red[4 + wv] = l;
    __syncthreads();
    l = (red[4] + red[5]) + (red[6] + red[7]);
    float c = m + logf(l);
#pragma unroll
    for (int i = 0; i < 125; ++i) rp[i * 256 + tid] = v[i] - c;
}

// ---------------------------------------------------------------------------
// Host orchestration
// ---------------------------------------------------------------------------
extern "C" void kernel_launch(void* const* d_in, const int* in_sizes, int n_in,
                              void* d_out, int out_size, void* d_ws, size_t ws_size,
                              hipStream_t stream)
{
    const int*   src        = (const int*)d_in[0];
    const int*   tgt        = (const int*)d_in[1];
    const float* tok_emb    = (const float*)d_in[2];
    const float* pos_emb    = (const float*)d_in[3];
    const float* enc_attn_w = (const float*)d_in[4];
    const float* enc_attn_b = (const float*)d_in[5];
    const float* enc_ffn_w1 = (const float*)d_in[6];
    const float* enc_ffn_b1 = (const float*)d_in[7];
    const float* enc_ffn_w2 = (const float*)d_in[8];
    const float* enc_ffn_b2 = (const float*)d_in[9];
    const float* enc_ln     = (const float*)d_in[10];
    const float* enc_fln    = (const float*)d_in[11];
    const float* dec_attn_w = (const float*)d_in[12];
    const float* dec_attn_b = (const float*)d_in[13];
    const float* dec_ffn_w1 = (const float*)d_in[14];
    const float* dec_ffn_b1 = (const float*)d_in[15];
    const float* dec_ffn_w2 = (const float*)d_in[16];
    const float* dec_ffn_b2 = (const float*)d_in[17];
    const float* dec_ln     = (const float*)d_in[18];
    const float* dec_fln    = (const float*)d_in[19];
    float* out = (float*)d_out;

    const size_t TOKD = (size_t)NTOK * D;
    const size_t DD   = (size_t)D * D;
    const size_t DF   = (size_t)D * FF;

    char* p = (char*)d_ws;
    auto carve = [&](size_t bytes) {
        void* r = (void*)p;
        p += (bytes + 255) & ~(size_t)255;
        return r;
    };
    u16* wtEA  = (u16*)carve(24 * DD * 2);
    u16* wtEF1 = (u16*)carve(6 * DF * 2);
    u16* wtEF2 = (u16*)carve(6 * DF * 2);
    u16* wtDA  = (u16*)carve(48 * DD * 2);
    u16* wtDF1 = (u16*)carve(6 * DF * 2);
    u16* wtDF2 = (u16*)carve(6 * DF * 2);
    float* xe  = (float*)carve(TOKD * 4);
    float* xd  = (float*)carve(TOKD * 4);
    u16* h16   = (u16*)carve(TOKD * 2);
    u16* q16   = (u16*)carve(TOKD * 2 * 3);
    u16* k16   = q16 + TOKD;
    u16* v16   = k16 + TOKD;
    u16* ao16  = (u16*)carve(TOKD * 2);
    u16* mem16 = (u16*)carve(TOKD * 2);
    u16* mid16 = (u16*)carve((size_t)NTOK * FF * 2);
    u16* kc16  = (u16*)carve(6 * TOKD * 2);
    u16* vc16  = (u16*)carve(6 * TOKD * 2);

    dim3 b256(256), b128(128), b64(64);
    dim3 gQKV(8, 32, 3);
    dim3 gP  (8, 32, 1);
    dim3 gKV6(8, 32, 6);
    dim3 gF1 (32, 16, 1);     // MT=64, N=2048
    dim3 gF2 (8, 32, 1);      // MT=32, K=2048
    dim3 gGen(8064, 1, 1);    // MT=64, XCD-swizzled flat grid (500x16 + 64 dummies)
    dim3 gAttn(4, H, B);

    // ---- preprocessing: weights -> bf16 [N,K] ----
    wconv_t<<<dim3(16, 16, 24), b256, 0, stream>>>(enc_attn_w, wtEA, 512, 512);
    wconv_t<<<dim3(64, 16, 6),  b256, 0, stream>>>(enc_ffn_w1, wtEF1, 512, 2048);
    wconv_t<<<dim3(16, 64, 6),  b256, 0, stream>>>(enc_ffn_w2, wtEF2, 2048, 512);
    wconv_t<<<dim3(16, 16, 48), b256, 0, stream>>>(dec_attn_w, wtDA, 512, 512);
    wconv_t<<<dim3(64, 16, 6),  b256, 0, stream>>>(dec_ffn_w1, wtDF1, 512, 2048);
    wconv_t<<<dim3(16, 64, 6),  b256, 0, stream>>>(dec_ffn_w2, wtDF2, 2048, 512);

    embed2_kernel<<<2 * NTOK, b256, 0, stream>>>(src, tgt, tok_emb, pos_emb, xe, xd);

    // ================= encoder =================
    for (int i = 0; i < NL; ++i) {
        const float* bb  = enc_attn_b + (size_t)i * 4 * D;
        const float* ln0 = enc_ln + (size_t)((i * 2 + 0) * 2) * D;
        const float* ln1 = enc_ln + (size_t)((i * 2 + 1) * 2) * D;

        gk<32><<<gQKV, b128, 0, stream>>>(nullptr, xe, ln0, ln0 + D,
            wtEA + (size_t)i * 4 * DD, bb, nullptr, q16,
            512, 512, 0, 1, 1, 0, 0, (long)DD, (long)D, (long)TOKD);
        attn_kernel<<<gAttn, b256, 0, stream>>>(q16, k16, v16, ao16, src, 0);
        gk<32><<<gP, b128, 0, stream>>>(ao16, nullptr, nullptr, nullptr,
            wtEA + (size_t)(i * 4 + 3) * DD, bb + 3 * D, xe, xe,
            512, 512, 0, 0, 0, 0, 0, 0, 0, 0);
        gk<64><<<gF1, b256, 0, stream>>>(nullptr, xe, ln1, ln1 + D,
            wtEF1 + (size_t)i * DF, enc_ffn_b1 + (size_t)i * FF, nullptr, mid16,
            512, 2048, 1, 1, 1, 0, 0, 0, 0, 0);
        gk<32><<<gF2, b128, 0, stream>>>(mid16, nullptr, nullptr, nullptr,
            wtEF2 + (size_t)i * DF, enc_ffn_b2 + (size_t)i * D, xe, xe,
            2048, 512, 0, 0, 0, 0, 0, 0, 0, 0);
    }
    ln_kernel<<<NTOK, b64, 0, stream>>>(xe, enc_fln, enc_fln + D, mem16);

    // cross-attn K,V for ALL 6 decoder layers (depend only on mem): 2 batched launches
    gk<32><<<gKV6, b128, 0, stream>>>(mem16, nullptr, nullptr, nullptr,
        wtDA + 5 * DD, dec_attn_b + 5 * D, nullptr, kc16,
        512, 512, 0, 1, 0, 0, 0, (long)(8 * DD), (long)(8 * D), (long)TOKD);
    gk<32><<<gKV6, b128, 0, stream>>>(mem16, nullptr, nullptr, nullptr,
        wtDA + 6 * DD, dec_attn_b + 6 * D, nullptr, vc16,
        512, 512, 0, 1, 0, 0, 0, (long)(8 * DD), (long)(8 * D), (long)TOKD);

    // ================= decoder =================
    for (int i = 0; i < NL; ++i) {
        const float* bb  = dec_attn_b + (size_t)i * 8 * D;
        const u16*   wt  = wtDA + (size_t)i * 8 * DD;
        const float* ln0 = dec_ln + (size_t)((i * 3 + 0) * 2) * D;
        const float* ln1 = dec_ln + (size_t)((i * 3 + 1) * 2) * D;
        const float* ln2 = dec_ln + (size_t)((i * 3 + 2) * 2) * D;

        // self-attention (causal)
        gk<32><<<gQKV, b128, 0, stream>>>(nullptr, xd, ln0, ln0 + D,
            wt, bb, nullptr, q16,
            512, 512, 0, 1, 1, 0, 0, (long)DD, (long)D, (long)TOKD);
        attn_kernel<<<gAttn, b256, 0, stream>>>(q16, k16, v16, ao16, tgt, 1);
        gk<32><<<gP, b128, 0, stream>>>(ao16, nullptr, nullptr, nullptr,
            wt + 3 * DD, bb + 3 * D, xd, xd,
            512, 512, 0, 0, 0, 0, 0, 0, 0, 0);

        // cross-attention
        gk<32><<<gP, b128, 0, stream>>>(nullptr, xd, ln1, ln1 + D,
            wt + 4 * DD, bb + 4 * D, nullptr, q16,
            512, 512, 0, 1, 1, 0, 0, 0, 0, 0);
        attn_kernel<<<gAttn, b256, 0, stream>>>(q16, kc16 + (size_t)i * TOKD,
            vc16 + (size_t)i * TOKD, ao16, src, 0);
        gk<32><<<gP, b128, 0, stream>>>(ao16, nullptr, nullptr, nullptr,
            wt + 7 * DD, bb + 7 * D, xd, xd,
            512, 512, 0, 0, 0, 0, 0, 0, 0, 0);

        // FFN
        gk<64><<<gF1, b256, 0, stream>>>(nullptr, xd, ln2, ln2 + D,
            wtDF1 + (size_t)i * DF, dec_ffn_b1 + (size_t)i * FF, nullptr, mid16,
            512, 2048, 1, 1, 1, 0, 0, 0, 0, 0);
        gk<32><<<gF2, b128, 0, stream>>>(mid16, nullptr, nullptr, nullptr,
            wtDF2 + (size_t)i * DF, dec_ffn_b2 + (size_t)i * D, xd, xd,
            2048, 512, 0, 0, 0, 0, 0, 0, 0, 0);
    }
    ln_kernel<<<NTOK, b64, 0, stream>>>(xd, dec_fln, dec_fln + D, h16);

    // ================= generator =================
    // B = tok_emb read directly as fp32 (bf32=1), XCD-chunked swizzle (swz=1)
    gk<64><<<gGen, b256, 0, stream>>>(h16, nullptr, nullptr, nullptr,
        tok_emb, nullptr, nullptr, out,
        512, V, 0, 0, 0, 1, 1, 0, 0, 0);
    lsm_kernel<<<NTOK, b256, 0, stream>>>(out);
}

// Round 3
// 1687.001 us; speedup vs baseline: 1.9001x; 1.7087x over previous
//
#include <hip/hip_runtime.h>
#include <hip/hip_bf16.h>

typedef unsigned short u16;
typedef unsigned int u32;
typedef __attribute__((ext_vector_type(8))) short bf8_t;  // 8 bf16 = 16B
typedef __attribute__((ext_vector_type(4))) float f4_t;

#define D 512
#define H 8
#define DK 64
#define NL 6
#define V 32000
#define FF 2048
#define B 8
#define S 128
#define NTOK (B * S)   // 1024

static __device__ inline u16 f2bs(float x) {
    __hip_bfloat16 h = __float2bfloat16(x);
    return *reinterpret_cast<u16*>(&h);
}
static __device__ inline float blo(u32 u) { return __uint_as_float(u << 16); }
static __device__ inline float bhi(u32 u) { return __uint_as_float(u & 0xffff0000u); }
static __device__ inline u32 pk2(float a, float b) {
    return ((u32)f2bs(b) << 16) | f2bs(a);
}

// ---------------------------------------------------------------------------
// Weight convert+transpose: in fp32 [R,C] -> out bf16 [C,R]   (z = matrix idx)
// ---------------------------------------------------------------------------
__global__ __launch_bounds__(256) void wconv_t(const float* __restrict__ in,
                                               u16* __restrict__ out,
                                               int R, int C)
{
    __shared__ u16 T[32][40];
    const float* inz = in + (size_t)blockIdx.z * R * C;
    u16* outz = out + (size_t)blockIdx.z * R * C;
    int r0 = blockIdx.y * 32, c0 = blockIdx.x * 32;
    int tid = threadIdx.x;
    {
        int r = tid >> 3, c4 = (tid & 7) * 4;
        float4 f = *(const float4*)&inz[(size_t)(r0 + r) * C + c0 + c4];
        T[c4 + 0][r] = f2bs(f.x);
        T[c4 + 1][r] = f2bs(f.y);
        T[c4 + 2][r] = f2bs(f.z);
        T[c4 + 3][r] = f2bs(f.w);
    }
    __syncthreads();
    {
        int c = tid >> 3, r4 = (tid & 7) * 4;
        u32 lo = ((u32)T[c][r4 + 1] << 16) | T[c][r4 + 0];
        u32 hi = ((u32)T[c][r4 + 3] << 16) | T[c][r4 + 2];
        uint2 p; p.x = lo; p.y = hi;
        *(uint2*)&outz[(size_t)(c0 + c) * R + r0 + r4] = p;
    }
}

// ---------------------------------------------------------------------------
// Elementwise fp32 -> bf16 (tok_emb), 4 elts/thread
// ---------------------------------------------------------------------------
__global__ __launch_bounds__(256) void ec_kernel(const float* __restrict__ in,
                                                 u16* __restrict__ out)
{
    size_t i = ((size_t)blockIdx.x * 256 + threadIdx.x) * 4;
    float4 f = *(const float4*)&in[i];
    uint2 p;
    p.x = pk2(f.x, f.y);
    p.y = pk2(f.z, f.w);
    *(uint2*)&out[i] = p;
}

// ---------------------------------------------------------------------------
// Both embeddings in one launch. blocks [0,1024) -> src/xe, [1024,2048) -> tgt/xd
// ---------------------------------------------------------------------------
__global__ __launch_bounds__(256) void embed2_kernel(
    const int* __restrict__ src, const int* __restrict__ tgt,
    const float* __restrict__ tok, const float* __restrict__ pos,
    float* __restrict__ xe, float* __restrict__ xd)
{
    int row = blockIdx.x;
    const int* ids; float* X; int r;
    if (row < NTOK) { ids = src; X = xe; r = row; }
    else            { ids = tgt; X = xd; r = row - NTOK; }
    int s  = r & (S - 1);
    int id = ids[r];
    int d  = threadIdx.x * 2;
    float2 t = *(const float2*)&tok[(size_t)id * D + d];
    float2 p = *(const float2*)&pos[(size_t)s * D + d];
    float2 o; o.x = t.x + p.x; o.y = t.y + p.y;
    *(float2*)&X[(size_t)r * D + d] = o;
}

// ---------------------------------------------------------------------------
// LayerNorm: fp32 in, bf16 out. One wave per row. (only for mem / final dec)
// ---------------------------------------------------------------------------
__global__ void ln_kernel(const float* __restrict__ X,
                          const float* __restrict__ g,
                          const float* __restrict__ bta,
                          u16* __restrict__ Y)
{
    int row  = blockIdx.x;
    int lane = threadIdx.x;          // 64
    float v[8];
    float sum = 0.f;
#pragma unroll
    for (int i = 0; i < 8; ++i) {
        v[i] = X[row * D + i * 64 + lane];
        sum += v[i];
    }
#pragma unroll
    for (int off = 32; off > 0; off >>= 1) sum += __shfl_xor(sum, off);
    float mu = sum * (1.f / D);
    float var = 0.f;
#pragma unroll
    for (int i = 0; i < 8; ++i) { float d = v[i] - mu; var += d * d; }
#pragma unroll
    for (int off = 32; off > 0; off >>= 1) var += __shfl_xor(var, off);
    var *= (1.f / D);
    float r = rsqrtf(var + 1e-6f);
#pragma unroll
    for (int i = 0; i < 8; ++i) {
        int d = i * 64 + lane;
        Y[row * D + d] = f2bs((v[i] - mu) * r * g[d] + bta[d]);
    }
}

// ---------------------------------------------------------------------------
// MFMA GEMM, NT: C = A[1024,K] @ Bt[z][N,K]^T + bias (+resid fp32) (+relu)
// 256 threads always. MT=32: waves split 2x2 over the 32x64 tile (acc[2]);
// MT=64: 4 waves stacked on rows (acc[4]).
// KC=128 chunks, software-pipelined: next chunk's global loads are issued
// (into registers) right after the barrier, before the MFMA cluster, so the
// HBM/L2 latency hides under compute — one exposure per kernel, not K/KC.
// LNA: A is fp32; per-row mean/rstd pre-pass; g/beta staged once in LDS;
//      normalize+cast happens at ds_write time (fuses the LayerNorm).
// swz: XCD-chunked flat grid for the generator (B col-tile pinned to 1 XCD).
// LDS row stride KC+8=136 shorts = 68 dwords == 4 (mod 32): 2-way-free.
// ---------------------------------------------------------------------------
template<int MT, int KC, int LNA>
__global__ __launch_bounds__(256) void gk(
    const u16* __restrict__ Abf, const float* __restrict__ Axf,
    const float* __restrict__ g, const float* __restrict__ be,
    const u16* __restrict__ Bt, const float* __restrict__ bias,
    const float* __restrict__ resid, void* __restrict__ Cout,
    int K, int N, int relu, int obf, int swz,
    long wzs, long bzs, long ozs)
{
    constexpr int THREADS = 256;
    constexpr int SL = KC / 8;                 // 16B slots per row (16)
    constexpr int NA = MT * SL / THREADS;      // A 16B loads / thread (2 or 4)
    constexpr int NB = 64 * SL / THREADS;      // B 16B loads / thread (4)
    constexpr int NJ = (MT == 32) ? 2 : 4;
    constexpr int TPR = THREADS / MT;          // threads per row for stats
    __shared__ __align__(16) u16 As[MT][KC + 8];
    __shared__ __align__(16) u16 Bs[64][KC + 8];
    __shared__ float muS[MT], rsS[MT];
    __shared__ float gS[LNA ? D : 4], beS[LNA ? D : 4];

    int tid = threadIdx.x;
    int col0, row0, z;
    if (swz) {
        int id = blockIdx.x;
        int s = id & 7, t = id >> 3;
        int r = t & 15, q = t >> 4;
        int c = q * 8 + s;
        if (c >= 500) return;
        col0 = c * 64; row0 = r * MT; z = 0;
    } else {
        col0 = blockIdx.x * 64; row0 = blockIdx.y * MT; z = blockIdx.z;
    }

    const float* bz = bias ? bias + (size_t)z * bzs : nullptr;
    const u16* Bz = Bt + (size_t)z * wzs;

    int wv  = tid >> 6, ln = tid & 63;
    int m16 = ln & 15, quad = ln >> 4;
    int rb  = (MT == 32) ? (wv & 1) * 16 : wv * 16;   // wave row base in tile
    int cb  = (MT == 32) ? (wv >> 1) * 32 : 0;        // wave col base in tile

    bf8_t  pA[LNA ? 1 : NA];
    float4 pAf[LNA ? 2 * NA : 1];
    bf8_t  pB[NB];

    auto loadA = [&](int kc) {
#pragma unroll
        for (int i = 0; i < NA; ++i) {
            int idx = tid + i * THREADS;
            int m = idx / SL, s8 = (idx % SL) * 8;
            if constexpr (LNA) {
                const float* sp = &Axf[(size_t)(row0 + m) * D + kc + s8];
                pAf[2 * i]     = *(const float4*)sp;
                pAf[2 * i + 1] = *(const float4*)(sp + 4);
            } else {
                pA[i] = *(const bf8_t*)&Abf[(size_t)(row0 + m) * K + kc + s8];
            }
        }
    };
    auto loadB = [&](int kc) {
#pragma unroll
        for (int i = 0; i < NB; ++i) {
            int idx = tid + i * THREADS;
            int n = idx / SL, s8 = (idx % SL) * 8;
            pB[i] = *(const bf8_t*)&Bz[(size_t)(col0 + n) * K + kc + s8];
        }
    };
    auto writeLDS = [&](int kc) {
#pragma unroll
        for (int i = 0; i < NA; ++i) {
            int idx = tid + i * THREADS;
            int m = idx / SL, s8 = (idx % SL) * 8;
            if constexpr (LNA) {
                float mu = muS[m], rs = rsS[m];
                float4 f0 = pAf[2 * i], f1 = pAf[2 * i + 1];
                float4 g0 = *(const float4*)&gS[kc + s8];
                float4 g1 = *(const float4*)&gS[kc + s8 + 4];
                float4 b0 = *(const float4*)&beS[kc + s8];
                float4 b1 = *(const float4*)&beS[kc + s8 + 4];
                uint4 o;
                o.x = pk2((f0.x - mu) * rs * g0.x + b0.x, (f0.y - mu) * rs * g0.y + b0.y);
                o.y = pk2((f0.z - mu) * rs * g0.z + b0.z, (f0.w - mu) * rs * g0.w + b0.w);
                o.z = pk2((f1.x - mu) * rs * g1.x + b1.x, (f1.y - mu) * rs * g1.y + b1.y);
                o.w = pk2((f1.z - mu) * rs * g1.z + b1.z, (f1.w - mu) * rs * g1.w + b1.w);
                *(uint4*)&As[m][s8] = o;
            } else {
                *(bf8_t*)&As[m][s8] = pA[i];
            }
        }
#pragma unroll
        for (int i = 0; i < NB; ++i) {
            int idx = tid + i * THREADS;
            int n = idx / SL, s8 = (idx % SL) * 8;
            *(bf8_t*)&Bs[n][s8] = pB[i];
        }
    };

    // ---- prologue: issue chunk-0 loads, then (LNA) stats while in flight ----
    loadA(0);
    loadB(0);
    if constexpr (LNA) {
        if (tid < 128) *(float4*)&gS[tid * 4] = *(const float4*)&g[tid * 4];
        else           *(float4*)&beS[(tid - 128) * 4] = *(const float4*)&be[(tid - 128) * 4];
        int r = tid / TPR, sR = tid % TPR;
        const float* xr = Axf + (size_t)(row0 + r) * D;
        float sum = 0.f, ss = 0.f;
#pragma unroll
        for (int c = 0; c < D / (TPR * 4); ++c) {
            float4 f = *(const float4*)&xr[c * TPR * 4 + sR * 4];
            sum += f.x + f.y + f.z + f.w;
            ss  += f.x * f.x + f.y * f.y + f.z * f.z + f.w * f.w;
        }
#pragma unroll
        for (int o = 1; o < TPR; o <<= 1) {
            sum += __shfl_xor(sum, o);
            ss  += __shfl_xor(ss, o);
        }
        if (sR == 0) {
            float mu  = sum * (1.f / D);
            float var = ss * (1.f / D) - mu * mu;
            muS[r] = mu;
            rsS[r] = rsqrtf(var + 1e-6f);
        }
        __syncthreads();
    }

    f4_t acc[NJ];
#pragma unroll
    for (int j = 0; j < NJ; ++j) acc[j] = (f4_t){0.f, 0.f, 0.f, 0.f};

    // ---- pipelined K loop ----
    for (int kc = 0; kc < K; kc += KC) {
        writeLDS(kc);
        __syncthreads();
        if (kc + KC < K) { loadA(kc + KC); loadB(kc + KC); }
#pragma unroll
        for (int ks = 0; ks < KC / 32; ++ks) {
            bf8_t a = *(const bf8_t*)&As[rb + m16][ks * 32 + quad * 8];
#pragma unroll
            for (int j = 0; j < NJ; ++j) {
                bf8_t b = *(const bf8_t*)&Bs[cb + j * 16 + m16][ks * 32 + quad * 8];
                acc[j] = __builtin_amdgcn_mfma_f32_16x16x32_bf16(a, b, acc[j], 0, 0, 0);
            }
        }
        __syncthreads();
    }

    // ---- epilogue ----
#pragma unroll
    for (int j = 0; j < NJ; ++j) {
        int col = col0 + cb + j * 16 + m16;
        float bv = bz ? bz[col] : 0.f;
#pragma unroll
        for (int r = 0; r < 4; ++r) {
            int row = row0 + rb + quad * 4 + r;
            float val = acc[j][r] + bv;
            if (resid) val += resid[(size_t)row * N + col];
            if (relu) val = fmaxf(val, 0.f);
            if (obf) ((u16*)Cout + (size_t)z * ozs)[(size_t)row * N + col] = f2bs(val);
            else     ((float*)Cout + (size_t)z * ozs)[(size_t)row * N + col] = val;
        }
    }
}

// ---------------------------------------------------------------------------
// Attention, bf16 I/O. Block = (qc,h,b), 256 thr = 4 waves, wave owns 8 q-rows.
// ---------------------------------------------------------------------------
__global__ __launch_bounds__(256) void attn_kernel(
    const u16* __restrict__ Qb, const u16* __restrict__ Kb,
    const u16* __restrict__ Vb, u16* __restrict__ Ob,
    const int* __restrict__ mask_ids, int causal)
{
    __shared__ u16 Ks[128][66];
    __shared__ u32 Vp[128][36];
    __shared__ u16 Qs[32][66];
    __shared__ float es[4][132];

    int qc = blockIdx.x;
    int h  = blockIdx.y;
    int b  = blockIdx.z;
    int tid = threadIdx.x;

    for (int i = tid; i < 1024; i += 256) {
        int t = i >> 3, d8 = (i & 7) * 8;
        size_t src = (size_t)(b * S + t) * D + h * DK + d8;
        uint4 kv = *(const uint4*)&Kb[src];
        *(u32*)&Ks[t][d8 + 0] = kv.x;
        *(u32*)&Ks[t][d8 + 2] = kv.y;
        *(u32*)&Ks[t][d8 + 4] = kv.z;
        *(u32*)&Ks[t][d8 + 6] = kv.w;
        uint4 vv = *(const uint4*)&Vb[src];
        *(uint4*)&Vp[t][d8 >> 1] = vv;
    }
    {
        int m = tid >> 3, d8 = (tid & 7) * 8;
        uint4 qv = *(const uint4*)&Qb[(size_t)(b * S + qc * 32 + m) * D + h * DK + d8];
        *(u32*)&Qs[m][d8 + 0] = qv.x;
        *(u32*)&Qs[m][d8 + 2] = qv.y;
        *(u32*)&Qs[m][d8 + 4] = qv.z;
        *(u32*)&Qs[m][d8 + 6] = qv.w;
    }
    __syncthreads();

    int w      = tid >> 6;
    int lane   = tid & 63;
    int d2     = lane & 31;
    int th     = lane >> 5;
    bool pad0  = (mask_ids[b * S + lane] == 1);
    bool pad1  = (mask_ids[b * S + 64 + lane] == 1);

    for (int qi = 0; qi < 8; ++qi) {
        int qloc = w * 8 + qi;
        int qpos = qc * 32 + qloc;

        float s0 = 0.f, s1 = 0.f;
#pragma unroll
        for (int i = 0; i < 32; ++i) {
            u32 qu = *(const u32*)&Qs[qloc][2 * i];
            u32 k0 = *(const u32*)&Ks[lane][2 * i];
            u32 k1 = *(const u32*)&Ks[lane + 64][2 * i];
            float ql = blo(qu), qh = bhi(qu);
            s0 += ql * blo(k0) + qh * bhi(k0);
            s1 += ql * blo(k1) + qh * bhi(k1);
        }
        s0 *= 0.125f; s1 *= 0.125f;
        if (pad0 || (causal && lane > qpos))        s0 = -1e30f;
        if (pad1 || (causal && (lane + 64) > qpos)) s1 = -1e30f;

        float mx = fmaxf(s0, s1);
#pragma unroll
        for (int off = 32; off > 0; off >>= 1) mx = fmaxf(mx, __shfl_xor(mx, off));
        float e0 = __expf(s0 - mx), e1 = __expf(s1 - mx);
        float l = e0 + e1;
#pragma unroll
        for (int off = 32; off > 0; off >>= 1) l += __shfl_xor(l, off);
        float inv = 1.f / l;
        es[w][lane]      = e0 * inv;
        es[w][lane + 64] = e1 * inv;

        float o0 = 0.f, o1 = 0.f;
#pragma unroll 8
        for (int i = 0; i < 64; ++i) {
            int t = th * 64 + i;
            float e = es[w][t];
            u32 vu = Vp[t][d2];
            o0 += e * blo(vu);
            o1 += e * bhi(vu);
        }
        o0 += __shfl_xor(o0, 32);
        o1 += __shfl_xor(o1, 32);
        if (th == 0) {
            u32 packed = ((u32)f2bs(o1) << 16) | f2bs(o0);
            *(u32*)&Ob[(size_t)(b * S + qpos) * D + h * DK + 2 * d2] = packed;
        }
    }
}

// ---------------------------------------------------------------------------
// Fused log-softmax: one block per row, 125 elements/thread held in registers.
// ---------------------------------------------------------------------------
__global__ __launch_bounds__(256) void lsm_kernel(float* __restrict__ out)
{
    __shared__ float red[8];
    int row = blockIdx.x, tid = threadIdx.x;
    float* rp = out + (size_t)row * V;
    float v[125];
    float m = -1e30f;
#pragma unroll
    for (int i = 0; i < 125; ++i) {
        v[i] = rp[i * 256 + tid];
        m = fmaxf(m, v[i]);
    }
#pragma unroll
    for (int off = 32; off > 0; off >>= 1) m = fmaxf(m, __shfl_xor(m, off));
    int wv = tid >> 6;
    if ((tid & 63) == 0) red[wv] = m;
    __syncthreads();
    m = fmaxf(fmaxf(red[0], red[1]), fmaxf(red[2], red[3]));
    float l = 0.f;
#pragma unroll
    for (int i = 0; i < 125; ++i) l += __expf(v[i] - m);
#pragma unroll
    for (int off = 32; off > 0; off >>= 1) l += __shfl_xor(l, off);
    if ((tid & 63) == 0) red[4 + wv] = l;
    __syncthreads();
    l = (red[4] + red[5]) + (red[6] + red[7]);
    float c = m + logf(l);
#pragma unroll
    for (int i = 0; i < 125; ++i) rp[i * 256 + tid] = v[i] - c;
}

// ---------------------------------------------------------------------------
// Host orchestration
// ---------------------------------------------------------------------------
extern "C" void kernel_launch(void* const* d_in, const int* in_sizes, int n_in,
                              void* d_out, int out_size, void* d_ws, size_t ws_size,
                              hipStream_t stream)
{
    const int*   src        = (const int*)d_in[0];
    const int*   tgt        = (const int*)d_in[1];
    const float* tok_emb    = (const float*)d_in[2];
    const float* pos_emb    = (const float*)d_in[3];
    const float* enc_attn_w = (const float*)d_in[4];
    const float* enc_attn_b = (const float*)d_in[5];
    const float* enc_ffn_w1 = (const float*)d_in[6];
    const float* enc_ffn_b1 = (const float*)d_in[7];
    const float* enc_ffn_w2 = (const float*)d_in[8];
    const float* enc_ffn_b2 = (const float*)d_in[9];
    const float* enc_ln     = (const float*)d_in[10];
    const float* enc_fln    = (const float*)d_in[11];
    const float* dec_attn_w = (const float*)d_in[12];
    const float* dec_attn_b = (const float*)d_in[13];
    const float* dec_ffn_w1 = (const float*)d_in[14];
    const float* dec_ffn_b1 = (const float*)d_in[15];
    const float* dec_ffn_w2 = (const float*)d_in[16];
    const float* dec_ffn_b2 = (const float*)d_in[17];
    const float* dec_ln     = (const float*)d_in[18];
    const float* dec_fln    = (const float*)d_in[19];
    float* out = (float*)d_out;

    const size_t TOKD = (size_t)NTOK * D;
    const size_t DD   = (size_t)D * D;
    const size_t DF   = (size_t)D * FF;

    char* p = (char*)d_ws;
    auto carve = [&](size_t bytes) {
        void* r = (void*)p;
        p += (bytes + 255) & ~(size_t)255;
        return r;
    };
    u16* wtEA  = (u16*)carve(24 * DD * 2);
    u16* wtEF1 = (u16*)carve(6 * DF * 2);
    u16* wtEF2 = (u16*)carve(6 * DF * 2);
    u16* wtDA  = (u16*)carve(48 * DD * 2);
    u16* wtDF1 = (u16*)carve(6 * DF * 2);
    u16* wtDF2 = (u16*)carve(6 * DF * 2);
    u16* emb16 = (u16*)carve((size_t)V * D * 2);
    float* xe  = (float*)carve(TOKD * 4);
    float* xd  = (float*)carve(TOKD * 4);
    u16* h16   = (u16*)carve(TOKD * 2);
    u16* q16   = (u16*)carve(TOKD * 2 * 3);
    u16* k16   = q16 + TOKD;
    u16* v16   = k16 + TOKD;
    u16* ao16  = (u16*)carve(TOKD * 2);
    u16* mem16 = (u16*)carve(TOKD * 2);
    u16* mid16 = (u16*)carve((size_t)NTOK * FF * 2);
    u16* kc16  = (u16*)carve(6 * TOKD * 2);
    u16* vc16  = (u16*)carve(6 * TOKD * 2);

    dim3 b256(256), b64(64);
    dim3 gQKV(8, 32, 3);
    dim3 gP  (8, 32, 1);
    dim3 gKV6(8, 32, 6);
    dim3 gF1 (32, 16, 1);     // MT=64, N=2048
    dim3 gF2 (8, 32, 1);      // MT=32, K=2048
    dim3 gGen(8064, 1, 1);    // MT=64, XCD-swizzled flat grid (500x16 + dummies)
    dim3 gAttn(4, H, B);

    // ---- preprocessing ----
    wconv_t<<<dim3(16, 16, 24), b256, 0, stream>>>(enc_attn_w, wtEA, 512, 512);
    wconv_t<<<dim3(64, 16, 6),  b256, 0, stream>>>(enc_ffn_w1, wtEF1, 512, 2048);
    wconv_t<<<dim3(16, 64, 6),  b256, 0, stream>>>(enc_ffn_w2, wtEF2, 2048, 512);
    wconv_t<<<dim3(16, 16, 48), b256, 0, stream>>>(dec_attn_w, wtDA, 512, 512);
    wconv_t<<<dim3(64, 16, 6),  b256, 0, stream>>>(dec_ffn_w1, wtDF1, 512, 2048);
    wconv_t<<<dim3(16, 64, 6),  b256, 0, stream>>>(dec_ffn_w2, wtDF2, 2048, 512);
    ec_kernel<<<16000, b256, 0, stream>>>(tok_emb, emb16);

    embed2_kernel<<<2 * NTOK, b256, 0, stream>>>(src, tgt, tok_emb, pos_emb, xe, xd);

    // ================= encoder =================
    for (int i = 0; i < NL; ++i) {
        const float* bb  = enc_attn_b + (size_t)i * 4 * D;
        const float* ln0 = enc_ln + (size_t)((i * 2 + 0) * 2) * D;
        const float* ln1 = enc_ln + (size_t)((i * 2 + 1) * 2) * D;

        gk<32, 128, 1><<<gQKV, b256, 0, stream>>>(nullptr, xe, ln0, ln0 + D,
            wtEA + (size_t)i * 4 * DD, bb, nullptr, q16,
            512, 512, 0, 1, 0, (long)DD, (long)D, (long)TOKD);
        attn_kernel<<<gAttn, b256, 0, stream>>>(q16, k16, v16, ao16, src, 0);
        gk<32, 128, 0><<<gP, b256, 0, stream>>>(ao16, nullptr, nullptr, nullptr,
            wtEA + (size_t)(i * 4 + 3) * DD, bb + 3 * D, xe, xe,
            512, 512, 0, 0, 0, 0, 0, 0);
        gk<64, 128, 1><<<gF1, b256, 0, stream>>>(nullptr, xe, ln1, ln1 + D,
            wtEF1 + (size_t)i * DF, enc_ffn_b1 + (size_t)i * FF, nullptr, mid16,
            512, 2048, 1, 1, 0, 0, 0, 0);
        gk<32, 128, 0><<<gF2, b256, 0, stream>>>(mid16, nullptr, nullptr, nullptr,
            wtEF2 + (size_t)i * DF, enc_ffn_b2 + (size_t)i * D, xe, xe,
            2048, 512, 0, 0, 0, 0, 0, 0);
    }
    ln_kernel<<<NTOK, b64, 0, stream>>>(xe, enc_fln, enc_fln + D, mem16);

    // cross-attn K,V for ALL 6 decoder layers: 2 batched launches
    gk<32, 128, 0><<<gKV6, b256, 0, stream>>>(mem16, nullptr, nullptr, nullptr,
        wtDA + 5 * DD, dec_attn_b + 5 * D, nullptr, kc16,
        512, 512, 0, 1, 0, (long)(8 * DD), (long)(8 * D), (long)TOKD);
    gk<32, 128, 0><<<gKV6, b256, 0, stream>>>(mem16, nullptr, nullptr, nullptr,
        wtDA + 6 * DD, dec_attn_b + 6 * D, nullptr, vc16,
        512, 512, 0, 1, 0, (long)(8 * DD), (long)(8 * D), (long)TOKD);

    // ================= decoder =================
    for (int i = 0; i < NL; ++i) {
        const float* bb  = dec_attn_b + (size_t)i * 8 * D;
        const u16*   wt  = wtDA + (size_t)i * 8 * DD;
        const float* ln0 = dec_ln + (size_t)((i * 3 + 0) * 2) * D;
        const float* ln1 = dec_ln + (size_t)((i * 3 + 1) * 2) * D;
        const float* ln2 = dec_ln + (size_t)((i * 3 + 2) * 2) * D;

        // self-attention (causal)
        gk<32, 128, 1><<<gQKV, b256, 0, stream>>>(nullptr, xd, ln0, ln0 + D,
            wt, bb, nullptr, q16,
            512, 512, 0, 1, 0, (long)DD, (long)D, (long)TOKD);
        attn_kernel<<<gAttn, b256, 0, stream>>>(q16, k16, v16, ao16, tgt, 1);
        gk<32, 128, 0><<<gP, b256, 0, stream>>>(ao16, nullptr, nullptr, nullptr,
            wt + 3 * DD, bb + 3 * D, xd, xd,
            512, 512, 0, 0, 0, 0, 0, 0);

        // cross-attention
        gk<32, 128, 1><<<gP, b256, 0, stream>>>(nullptr, xd, ln1, ln1 + D,
            wt + 4 * DD, bb + 4 * D, nullptr, q16,
            512, 512, 0, 1, 0, 0, 0, 0);
        attn_kernel<<<gAttn, b256, 0, stream>>>(q16, kc16 + (size_t)i * TOKD,
            vc16 + (size_t)i * TOKD, ao16, src, 0);
        gk<32, 128, 0><<<gP, b256, 0, stream>>>(ao16, nullptr, nullptr, nullptr,
            wt + 7 * DD, bb + 7 * D, xd, xd,
            512, 512, 0, 0, 0, 0, 0, 0);

        // FFN
        gk<64, 128, 1><<<gF1, b256, 0, stream>>>(nullptr, xd, ln2, ln2 + D,
            wtDF1 + (size_t)i * DF, dec_ffn_b1 + (size_t)i * FF, nullptr, mid16,
            512, 2048, 1, 1, 0, 0, 0, 0);
        gk<32, 128, 0><<<gF2, b256, 0, stream>>>(mid16, nullptr, nullptr, nullptr,
            wtDF2 + (size_t)i * DF, dec_ffn_b2 + (size_t)i * D, xd, xd,
            2048, 512, 0, 0, 0, 0, 0, 0);
    }
    ln_kernel<<<NTOK, b64, 0, stream>>>(xd, dec_fln, dec_fln + D, h16);

    // ================= generator =================
    gk<64, 128, 0><<<gGen, b256, 0, stream>>>(h16, nullptr, nullptr, nullptr,
        emb16, nullptr, nullptr, out,
        512, V, 0, 0, 1, 0, 0, 0);
    lsm_kernel<<<NTOK, b256, 0, stream>>>(out);
}

// Round 4
// 1600.230 us; speedup vs baseline: 2.0032x; 1.0542x over previous
//
#include <hip/hip_runtime.h>
#include <hip/hip_bf16.h>

typedef unsigned short u16;
typedef unsigned int u32;
typedef __attribute__((ext_vector_type(8))) short bf8_t;  // 8 bf16 = 16B
typedef __attribute__((ext_vector_type(4))) float f4_t;

#define D 512
#define H 8
#define DK 64
#define NL 6
#define V 32000
#define FF 2048
#define B 8
#define S 128
#define NTOK (B * S)   // 1024

static __device__ inline u16 f2bs(float x) {
    __hip_bfloat16 h = __float2bfloat16(x);
    return *reinterpret_cast<u16*>(&h);
}
static __device__ inline float blo(u32 u) { return __uint_as_float(u << 16); }
static __device__ inline float bhi(u32 u) { return __uint_as_float(u & 0xffff0000u); }
static __device__ inline u32 pk2(float a, float b) {
    return ((u32)f2bs(b) << 16) | f2bs(a);
}

// ---------------------------------------------------------------------------
// prep: ALL one-time preprocessing in ONE dispatch (flat-grid segments):
//   6x weight convert+transpose, tok_emb->bf16, both embeddings.
// ---------------------------------------------------------------------------
__device__ inline void wconv_body(const float* __restrict__ in, u16* __restrict__ out,
                                  int R, int C, int bx, int by, int bz, int tid,
                                  u16 (*T)[40])
{
    const float* inz = in + (size_t)bz * R * C;
    u16* outz = out + (size_t)bz * R * C;
    int r0 = by * 32, c0 = bx * 32;
    {
        int r = tid >> 3, c4 = (tid & 7) * 4;
        float4 f = *(const float4*)&inz[(size_t)(r0 + r) * C + c0 + c4];
        T[c4 + 0][r] = f2bs(f.x);
        T[c4 + 1][r] = f2bs(f.y);
        T[c4 + 2][r] = f2bs(f.z);
        T[c4 + 3][r] = f2bs(f.w);
    }
    __syncthreads();
    {
        int c = tid >> 3, r4 = (tid & 7) * 4;
        u32 lo = ((u32)T[c][r4 + 1] << 16) | T[c][r4 + 0];
        u32 hi = ((u32)T[c][r4 + 3] << 16) | T[c][r4 + 2];
        uint2 p; p.x = lo; p.y = hi;
        *(uint2*)&outz[(size_t)(c0 + c) * R + r0 + r4] = p;
    }
}

__global__ __launch_bounds__(256) void prep(
    const float* __restrict__ eaw, const float* __restrict__ ef1,
    const float* __restrict__ ef2, const float* __restrict__ daw,
    const float* __restrict__ df1, const float* __restrict__ df2,
    u16* __restrict__ wEA, u16* __restrict__ wEF1, u16* __restrict__ wEF2,
    u16* __restrict__ wDA, u16* __restrict__ wDF1, u16* __restrict__ wDF2,
    const float* __restrict__ tok, u16* __restrict__ emb16,
    const int* __restrict__ src, const int* __restrict__ tgt,
    const float* __restrict__ pos, float* __restrict__ xe, float* __restrict__ xd)
{
    __shared__ u16 T[32][40];
    int id = blockIdx.x, tid = threadIdx.x;
    if (id < 6144)  { wconv_body(eaw, wEA, 512, 512,  id % 16, (id / 16) % 16, id / 256,  tid, T); return; }
    id -= 6144;
    if (id < 6144)  { wconv_body(ef1, wEF1, 512, 2048, id % 64, (id / 64) % 16, id / 1024, tid, T); return; }
    id -= 6144;
    if (id < 6144)  { wconv_body(ef2, wEF2, 2048, 512, id % 16, (id / 16) % 64, id / 1024, tid, T); return; }
    id -= 6144;
    if (id < 12288) { wconv_body(daw, wDA, 512, 512,  id % 16, (id / 16) % 16, id / 256,  tid, T); return; }
    id -= 12288;
    if (id < 6144)  { wconv_body(df1, wDF1, 512, 2048, id % 64, (id / 64) % 16, id / 1024, tid, T); return; }
    id -= 6144;
    if (id < 6144)  { wconv_body(df2, wDF2, 2048, 512, id % 16, (id / 16) % 64, id / 1024, tid, T); return; }
    id -= 6144;
    if (id < 16000) {
        size_t i = ((size_t)id * 256 + tid) * 4;
        float4 f = *(const float4*)&tok[i];
        uint2 p;
        p.x = pk2(f.x, f.y);
        p.y = pk2(f.z, f.w);
        *(uint2*)&emb16[i] = p;
        return;
    }
    id -= 16000;
    {   // embed2: [0,1024)->src/xe, [1024,2048)->tgt/xd
        const int* ids; float* X; int r;
        if (id < NTOK) { ids = src; X = xe; r = id; }
        else           { ids = tgt; X = xd; r = id - NTOK; }
        int s  = r & (S - 1);
        int tk = ids[r];
        int d  = tid * 2;
        float2 t = *(const float2*)&tok[(size_t)tk * D + d];
        float2 p = *(const float2*)&pos[(size_t)s * D + d];
        float2 o; o.x = t.x + p.x; o.y = t.y + p.y;
        *(float2*)&X[(size_t)r * D + d] = o;
    }
}

// ---------------------------------------------------------------------------
// LayerNorm: fp32 in, bf16 out. One wave per row. (mem / final-dec only)
// ---------------------------------------------------------------------------
__global__ void ln_kernel(const float* __restrict__ X,
                          const float* __restrict__ g,
                          const float* __restrict__ bta,
                          u16* __restrict__ Y)
{
    int row  = blockIdx.x;
    int lane = threadIdx.x;          // 64
    float v[8];
    float sum = 0.f;
#pragma unroll
    for (int i = 0; i < 8; ++i) {
        v[i] = X[row * D + i * 64 + lane];
        sum += v[i];
    }
#pragma unroll
    for (int off = 32; off > 0; off >>= 1) sum += __shfl_xor(sum, off);
    float mu = sum * (1.f / D);
    float var = 0.f;
#pragma unroll
    for (int i = 0; i < 8; ++i) { float d = v[i] - mu; var += d * d; }
#pragma unroll
    for (int off = 32; off > 0; off >>= 1) var += __shfl_xor(var, off);
    var *= (1.f / D);
    float r = rsqrtf(var + 1e-6f);
#pragma unroll
    for (int i = 0; i < 8; ++i) {
        int d = i * 64 + lane;
        Y[row * D + d] = f2bs((v[i] - mu) * r * g[d] + bta[d]);
    }
}

// ---------------------------------------------------------------------------
// MFMA GEMM (as round 3, pipelined) + NEW fp32 LDS-transpose epilogue:
// fp32 outputs staged acc->LDS then stored as per-lane float4 (256B segments).
// ---------------------------------------------------------------------------
template<int MT, int KC, int LNA>
__global__ __launch_bounds__(256) void gk(
    const u16* __restrict__ Abf, const float* __restrict__ Axf,
    const float* __restrict__ g, const float* __restrict__ be,
    const u16* __restrict__ Bt, const float* __restrict__ bias,
    const float* __restrict__ resid, void* __restrict__ Cout,
    int K, int N, int relu, int obf, int swz,
    long wzs, long bzs, long ozs)
{
    constexpr int THREADS = 256;
    constexpr int SL = KC / 8;
    constexpr int NA = MT * SL / THREADS;
    constexpr int NB = 64 * SL / THREADS;
    constexpr int NJ = (MT == 32) ? 2 : 4;
    constexpr int TPR = THREADS / MT;
    __shared__ __align__(16) u16 AB[(MT + 64) * (KC + 8)];
    u16 (*As)[KC + 8] = (u16(*)[KC + 8])AB;
    u16 (*Bs)[KC + 8] = (u16(*)[KC + 8])&AB[MT * (KC + 8)];
    __shared__ float muS[MT], rsS[MT];
    __shared__ float gS[LNA ? D : 4], beS[LNA ? D : 4];

    int tid = threadIdx.x;
    int col0, row0, z;
    if (swz) {
        int id = blockIdx.x;
        int s = id & 7, t = id >> 3;
        int r = t & 15, q = t >> 4;
        int c = q * 8 + s;
        if (c >= 500) return;
        col0 = c * 64; row0 = r * MT; z = 0;
    } else {
        col0 = blockIdx.x * 64; row0 = blockIdx.y * MT; z = blockIdx.z;
    }

    const float* bz = bias ? bias + (size_t)z * bzs : nullptr;
    const u16* Bz = Bt + (size_t)z * wzs;

    int wv  = tid >> 6, ln = tid & 63;
    int m16 = ln & 15, quad = ln >> 4;
    int rb  = (MT == 32) ? (wv & 1) * 16 : wv * 16;
    int cb  = (MT == 32) ? (wv >> 1) * 32 : 0;

    bf8_t  pA[LNA ? 1 : NA];
    float4 pAf[LNA ? 2 * NA : 1];
    bf8_t  pB[NB];

    auto loadA = [&](int kc) {
#pragma unroll
        for (int i = 0; i < NA; ++i) {
            int idx = tid + i * THREADS;
            int m = idx / SL, s8 = (idx % SL) * 8;
            if constexpr (LNA) {
                const float* sp = &Axf[(size_t)(row0 + m) * D + kc + s8];
                pAf[2 * i]     = *(const float4*)sp;
                pAf[2 * i + 1] = *(const float4*)(sp + 4);
            } else {
                pA[i] = *(const bf8_t*)&Abf[(size_t)(row0 + m) * K + kc + s8];
            }
        }
    };
    auto loadB = [&](int kc) {
#pragma unroll
        for (int i = 0; i < NB; ++i) {
            int idx = tid + i * THREADS;
            int n = idx / SL, s8 = (idx % SL) * 8;
            pB[i] = *(const bf8_t*)&Bz[(size_t)(col0 + n) * K + kc + s8];
        }
    };
    auto writeLDS = [&](int kc) {
#pragma unroll
        for (int i = 0; i < NA; ++i) {
            int idx = tid + i * THREADS;
            int m = idx / SL, s8 = (idx % SL) * 8;
            if constexpr (LNA) {
                float mu = muS[m], rs = rsS[m];
                float4 f0 = pAf[2 * i], f1 = pAf[2 * i + 1];
                float4 g0 = *(const float4*)&gS[kc + s8];
                float4 g1 = *(const float4*)&gS[kc + s8 + 4];
                float4 b0 = *(const float4*)&beS[kc + s8];
                float4 b1 = *(const float4*)&beS[kc + s8 + 4];
                uint4 o;
                o.x = pk2((f0.x - mu) * rs * g0.x + b0.x, (f0.y - mu) * rs * g0.y + b0.y);
                o.y = pk2((f0.z - mu) * rs * g0.z + b0.z, (f0.w - mu) * rs * g0.w + b0.w);
                o.z = pk2((f1.x - mu) * rs * g1.x + b1.x, (f1.y - mu) * rs * g1.y + b1.y);
                o.w = pk2((f1.z - mu) * rs * g1.z + b1.z, (f1.w - mu) * rs * g1.w + b1.w);
                *(uint4*)&As[m][s8] = o;
            } else {
                *(bf8_t*)&As[m][s8] = pA[i];
            }
        }
#pragma unroll
        for (int i = 0; i < NB; ++i) {
            int idx = tid + i * THREADS;
            int n = idx / SL, s8 = (idx % SL) * 8;
            *(bf8_t*)&Bs[n][s8] = pB[i];
        }
    };

    loadA(0);
    loadB(0);
    if constexpr (LNA) {
        if (tid < 128) *(float4*)&gS[tid * 4] = *(const float4*)&g[tid * 4];
        else           *(float4*)&beS[(tid - 128) * 4] = *(const float4*)&be[(tid - 128) * 4];
        int r = tid / TPR, sR = tid % TPR;
        const float* xr = Axf + (size_t)(row0 + r) * D;
        float sum = 0.f, ss = 0.f;
#pragma unroll
        for (int c = 0; c < D / (TPR * 4); ++c) {
            float4 f = *(const float4*)&xr[c * TPR * 4 + sR * 4];
            sum += f.x + f.y + f.z + f.w;
            ss  += f.x * f.x + f.y * f.y + f.z * f.z + f.w * f.w;
        }
#pragma unroll
        for (int o = 1; o < TPR; o <<= 1) {
            sum += __shfl_xor(sum, o);
            ss  += __shfl_xor(ss, o);
        }
        if (sR == 0) {
            float mu  = sum * (1.f / D);
            float var = ss * (1.f / D) - mu * mu;
            muS[r] = mu;
            rsS[r] = rsqrtf(var + 1e-6f);
        }
        __syncthreads();
    }

    f4_t acc[NJ];
#pragma unroll
    for (int j = 0; j < NJ; ++j) acc[j] = (f4_t){0.f, 0.f, 0.f, 0.f};

    for (int kc = 0; kc < K; kc += KC) {
        writeLDS(kc);
        __syncthreads();
        if (kc + KC < K) { loadA(kc + KC); loadB(kc + KC); }
#pragma unroll
        for (int ks = 0; ks < KC / 32; ++ks) {
            bf8_t a = *(const bf8_t*)&As[rb + m16][ks * 32 + quad * 8];
#pragma unroll
            for (int j = 0; j < NJ; ++j) {
                bf8_t b = *(const bf8_t*)&Bs[cb + j * 16 + m16][ks * 32 + quad * 8];
                acc[j] = __builtin_amdgcn_mfma_f32_16x16x32_bf16(a, b, acc[j], 0, 0, 0);
            }
        }
        __syncthreads();
    }

    if (obf) {
#pragma unroll
        for (int j = 0; j < NJ; ++j) {
            int col = col0 + cb + j * 16 + m16;
            float bv = bz ? bz[col] : 0.f;
#pragma unroll
            for (int r = 0; r < 4; ++r) {
                int row = row0 + rb + quad * 4 + r;
                float val = acc[j][r] + bv;
                if (relu) val = fmaxf(val, 0.f);
                ((u16*)Cout + (size_t)z * ozs)[(size_t)row * N + col] = f2bs(val);
            }
        }
    } else {
        float (*Cs)[68] = (float(*)[68])AB;
#pragma unroll
        for (int j = 0; j < NJ; ++j)
#pragma unroll
            for (int r = 0; r < 4; ++r)
                Cs[rb + quad * 4 + r][cb + j * 16 + m16] = acc[j][r];
        __syncthreads();
        float* Co = (float*)Cout + (size_t)z * ozs;
#pragma unroll
        for (int i = 0; i < MT / 16; ++i) {
            int flat = (i * 256 + tid) * 4;
            int row = flat >> 6, col = flat & 63;
            float4 v = *(const float4*)&Cs[row][col];
            if (bz) {
                float4 b4 = *(const float4*)&bz[col0 + col];
                v.x += b4.x; v.y += b4.y; v.z += b4.z; v.w += b4.w;
            }
            if (resid) {
                float4 r4 = *(const float4*)&resid[(size_t)(row0 + row) * N + col0 + col];
                v.x += r4.x; v.y += r4.y; v.z += r4.z; v.w += r4.w;
            }
            if (relu) {
                v.x = fmaxf(v.x, 0.f); v.y = fmaxf(v.y, 0.f);
                v.z = fmaxf(v.z, 0.f); v.w = fmaxf(v.w, 0.f);
            }
            *(float4*)&Co[(size_t)(row0 + row) * N + col0 + col] = v;
        }
    }
}

// ---------------------------------------------------------------------------
// fqa: fused LN + QKV head-projection + self-attention.
// Block = (qc, h, b), 512 thr = 8 waves. K/V projected for all 128 tokens
// (4x duplicated across qc — MFMA is ~3% of block time), Q for the 32 q-rows.
// ---------------------------------------------------------------------------
__global__ __launch_bounds__(512) void fqa(
    const float* __restrict__ X, const float* __restrict__ g,
    const float* __restrict__ be, const u16* __restrict__ W,
    const float* __restrict__ bb, u16* __restrict__ Ob,
    const int* __restrict__ mask_ids, int causal)
{
    __shared__ __align__(16) u16 As[128][72];
    __shared__ __align__(16) u16 Ws[3][64][72];
    __shared__ u16 Ks[128][66];
    __shared__ u32 Vp[128][36];
    __shared__ u16 Qs[32][66];
    __shared__ float es[8][132];
    __shared__ float muS[128], rsS[128];
    __shared__ float gS[D], beS[D];

    int qc = blockIdx.x, h = blockIdx.y, b = blockIdx.z;
    int tid = threadIdx.x;
    int w = tid >> 6, lane = tid & 63;
    int m16 = lane & 15, quad = lane >> 4;
    const float* Xb = X + (size_t)(b * S) * D;
    const size_t DDs = (size_t)D * D;

    float4 pAf[4];
    bf8_t  pW[3];
    auto loadA = [&](int kc) {
#pragma unroll
        for (int i = 0; i < 2; ++i) {
            int idx = tid + i * 512;
            int m = idx >> 3, s8 = (idx & 7) * 8;
            const float* sp = &Xb[(size_t)m * D + kc + s8];
            pAf[2 * i]     = *(const float4*)sp;
            pAf[2 * i + 1] = *(const float4*)(sp + 4);
        }
    };
    auto loadW = [&](int kc) {
        int n = tid >> 3, s8 = (tid & 7) * 8;
#pragma unroll
        for (int m = 0; m < 3; ++m)
            pW[m] = *(const bf8_t*)&W[m * DDs + (size_t)(h * 64 + n) * D + kc + s8];
    };
    auto writeLDS = [&](int kc) {
#pragma unroll
        for (int i = 0; i < 2; ++i) {
            int idx = tid + i * 512;
            int m = idx >> 3, s8 = (idx & 7) * 8;
            float mu = muS[m], rs = rsS[m];
            float4 f0 = pAf[2 * i], f1 = pAf[2 * i + 1];
            float4 g0 = *(const float4*)&gS[kc + s8];
            float4 g1 = *(const float4*)&gS[kc + s8 + 4];
            float4 b0 = *(const float4*)&beS[kc + s8];
            float4 b1 = *(const float4*)&beS[kc + s8 + 4];
            uint4 o;
            o.x = pk2((f0.x - mu) * rs * g0.x + b0.x, (f0.y - mu) * rs * g0.y + b0.y);
            o.y = pk2((f0.z - mu) * rs * g0.z + b0.z, (f0.w - mu) * rs * g0.w + b0.w);
            o.z = pk2((f1.x - mu) * rs * g1.x + b1.x, (f1.y - mu) * rs * g1.y + b1.y);
            o.w = pk2((f1.z - mu) * rs * g1.z + b1.z, (f1.w - mu) * rs * g1.w + b1.w);
            *(uint4*)&As[m][s8] = o;
        }
        {
            int n = tid >> 3, s8 = (tid & 7) * 8;
#pragma unroll
            for (int m = 0; m < 3; ++m)
                *(bf8_t*)&Ws[m][n][s8] = pW[m];
        }
    };

    loadA(0);
    loadW(0);
    if (tid < 128)      *(float4*)&gS[tid * 4] = *(const float4*)&g[tid * 4];
    else if (tid < 256) *(float4*)&beS[(tid - 128) * 4] = *(const float4*)&be[(tid - 128) * 4];
    {   // LN stats: 4 threads per row
        int r = tid >> 2, sub = tid & 3;
        const float* xr = Xb + (size_t)r * D + sub * 128;
        float sum = 0.f, ss = 0.f;
#pragma unroll
        for (int c = 0; c < 32; ++c) {
            float4 f = *(const float4*)&xr[c * 4];
            sum += f.x + f.y + f.z + f.w;
            ss  += f.x * f.x + f.y * f.y + f.z * f.z + f.w * f.w;
        }
        sum += __shfl_xor(sum, 1); sum += __shfl_xor(sum, 2);
        ss  += __shfl_xor(ss, 1);  ss  += __shfl_xor(ss, 2);
        if (sub == 0) {
            float mu  = sum * (1.f / D);
            float var = ss * (1.f / D) - mu * mu;
            muS[r] = mu;
            rsS[r] = rsqrtf(var + 1e-6f);
        }
    }
    __syncthreads();

    f4_t accK[4], accV[4], accQ;
#pragma unroll
    for (int j = 0; j < 4; ++j) {
        accK[j] = (f4_t){0.f, 0.f, 0.f, 0.f};
        accV[j] = (f4_t){0.f, 0.f, 0.f, 0.f};
    }
    accQ = (f4_t){0.f, 0.f, 0.f, 0.f};

    for (int kc = 0; kc < 512; kc += 64) {
        writeLDS(kc);
        __syncthreads();
        if (kc < 448) { loadA(kc + 64); loadW(kc + 64); }
#pragma unroll
        for (int ks = 0; ks < 2; ++ks) {
            int ko = ks * 32 + quad * 8;
            bf8_t akv = *(const bf8_t*)&As[w * 16 + m16][ko];
            bf8_t aq  = *(const bf8_t*)&As[qc * 32 + (w & 1) * 16 + m16][ko];
#pragma unroll
            for (int j = 0; j < 4; ++j) {
                bf8_t bk = *(const bf8_t*)&Ws[1][j * 16 + m16][ko];
                accK[j] = __builtin_amdgcn_mfma_f32_16x16x32_bf16(akv, bk, accK[j], 0, 0, 0);
                bf8_t bv = *(const bf8_t*)&Ws[2][j * 16 + m16][ko];
                accV[j] = __builtin_amdgcn_mfma_f32_16x16x32_bf16(akv, bv, accV[j], 0, 0, 0);
            }
            bf8_t bq = *(const bf8_t*)&Ws[0][(w >> 1) * 16 + m16][ko];
            accQ = __builtin_amdgcn_mfma_f32_16x16x32_bf16(aq, bq, accQ, 0, 0, 0);
        }
        __syncthreads();
    }

    // write K, V(packed), Q to LDS with biases
    {
        const float* bq = bb + h * 64;
        const float* bk = bb + D + h * 64;
        const float* bv = bb + 2 * D + h * 64;
#pragma unroll
        for (int j = 0; j < 4; ++j) {
            int col = j * 16 + m16;
            float bkv = bk[col], bvv = bv[col];
#pragma unroll
            for (int r = 0; r < 4; ++r) {
                int row = w * 16 + quad * 4 + r;
                Ks[row][col] = f2bs(accK[j][r] + bkv);
                float vv = accV[j][r] + bvv;
                float vo = __shfl_xor(vv, 1);
                if ((m16 & 1) == 0)
                    Vp[row][j * 8 + (m16 >> 1)] = pk2(vv, vo);
            }
        }
        {
            int col = (w >> 1) * 16 + m16;
            float bqv = bq[col];
#pragma unroll
            for (int r = 0; r < 4; ++r)
                Qs[(w & 1) * 16 + quad * 4 + r][col] = f2bs(accQ[r] + bqv);
        }
    }
    __syncthreads();

    // attention: 8 waves x 4 q-rows
    int d2 = lane & 31, th = lane >> 5;
    bool pad0 = (mask_ids[b * S + lane] == 1);
    bool pad1 = (mask_ids[b * S + 64 + lane] == 1);

    for (int qi = 0; qi < 4; ++qi) {
        int qloc = w * 4 + qi;
        int qpos = qc * 32 + qloc;

        float s0 = 0.f, s1 = 0.f;
#pragma unroll
        for (int i = 0; i < 32; ++i) {
            u32 qu = *(const u32*)&Qs[qloc][2 * i];
            u32 k0 = *(const u32*)&Ks[lane][2 * i];
            u32 k1 = *(const u32*)&Ks[lane + 64][2 * i];
            float ql = blo(qu), qh = bhi(qu);
            s0 += ql * blo(k0) + qh * bhi(k0);
            s1 += ql * blo(k1) + qh * bhi(k1);
        }
        s0 *= 0.125f; s1 *= 0.125f;
        if (pad0 || (causal && lane > qpos))        s0 = -1e30f;
        if (pad1 || (causal && (lane + 64) > qpos)) s1 = -1e30f;

        float mx = fmaxf(s0, s1);
#pragma unroll
        for (int off = 32; off > 0; off >>= 1) mx = fmaxf(mx, __shfl_xor(mx, off));
        float e0 = __expf(s0 - mx), e1 = __expf(s1 - mx);
        float l = e0 + e1;
#pragma unroll
        for (int off = 32; off > 0; off >>= 1) l += __shfl_xor(l, off);
        float inv = 1.f / l;
        es[w][lane]      = e0 * inv;
        es[w][lane + 64] = e1 * inv;

        float o0 = 0.f, o1 = 0.f;
#pragma unroll 8
        for (int i = 0; i < 64; ++i) {
            int t = th * 64 + i;
            float e = es[w][t];
            u32 vu = Vp[t][d2];
            o0 += e * blo(vu);
            o1 += e * bhi(vu);
        }
        o0 += __shfl_xor(o0, 32);
        o1 += __shfl_xor(o1, 32);
        if (th == 0) {
            u32 packed = ((u32)f2bs(o1) << 16) | f2bs(o0);
            *(u32*)&Ob[(size_t)(b * S + qpos) * D + h * DK + 2 * d2] = packed;
        }
    }
}

// ---------------------------------------------------------------------------
// fca: fused LN + Q head-projection + cross-attention (K/V prebatched bf16).
// Block = (qc, h, b), 512 thr.
// ---------------------------------------------------------------------------
__global__ __launch_bounds__(512) void fca(
    const float* __restrict__ X, const float* __restrict__ g,
    const float* __restrict__ be, const u16* __restrict__ Wq,
    const float* __restrict__ bq, const u16* __restrict__ Kb,
    const u16* __restrict__ Vb, u16* __restrict__ Ob,
    const int* __restrict__ mask_ids)
{
    __shared__ __align__(16) u16 As[32][72];
    __shared__ __align__(16) u16 Wqs[64][72];
    __shared__ u16 Ks[128][66];
    __shared__ u32 Vp[128][36];
    __shared__ u16 Qs[32][66];
    __shared__ float es[8][132];
    __shared__ float muS[32], rsS[32];
    __shared__ float gS[D], beS[D];

    int qc = blockIdx.x, h = blockIdx.y, b = blockIdx.z;
    int tid = threadIdx.x;
    int w = tid >> 6, lane = tid & 63;
    int m16 = lane & 15, quad = lane >> 4;
    const float* Xb = X + (size_t)(b * S + qc * 32) * D;

    float4 pAf[2];
    bf8_t  pW;
    auto loadA = [&](int kc) {
        if (tid < 256) {
            int m = tid >> 3, s8 = (tid & 7) * 8;
            const float* sp = &Xb[(size_t)m * D + kc + s8];
            pAf[0] = *(const float4*)sp;
            pAf[1] = *(const float4*)(sp + 4);
        }
    };
    auto loadW = [&](int kc) {
        int n = tid >> 3, s8 = (tid & 7) * 8;
        pW = *(const bf8_t*)&Wq[(size_t)(h * 64 + n) * D + kc + s8];
    };
    auto writeLDS = [&](int kc) {
        if (tid < 256) {
            int m = tid >> 3, s8 = (tid & 7) * 8;
            float mu = muS[m], rs = rsS[m];
            float4 f0 = pAf[0], f1 = pAf[1];
            float4 g0 = *(const float4*)&gS[kc + s8];
            float4 g1 = *(const float4*)&gS[kc + s8 + 4];
            float4 b0 = *(const float4*)&beS[kc + s8];
            float4 b1 = *(const float4*)&beS[kc + s8 + 4];
            uint4 o;
            o.x = pk2((f0.x - mu) * rs * g0.x + b0.x, (f0.y - mu) * rs * g0.y + b0.y);
            o.y = pk2((f0.z - mu) * rs * g0.z + b0.z, (f0.w - mu) * rs * g0.w + b0.w);
            o.z = pk2((f1.x - mu) * rs * g1.x + b1.x, (f1.y - mu) * rs * g1.y + b1.y);
            o.w = pk2((f1.z - mu) * rs * g1.z + b1.z, (f1.w - mu) * rs * g1.w + b1.w);
            *(uint4*)&As[m][s8] = o;
        }
        {
            int n = tid >> 3, s8 = (tid & 7) * 8;
            *(bf8_t*)&Wqs[n][s8] = pW;
        }
    };

    loadA(0);
    loadW(0);
    // stage K/V (128 tokens)
    for (int i = tid; i < 1024; i += 512) {
        int t = i >> 3, d8 = (i & 7) * 8;
        size_t src = (size_t)(b * S + t) * D + h * DK + d8;
        uint4 kv = *(const uint4*)&Kb[src];
        *(u32*)&Ks[t][d8 + 0] = kv.x;
        *(u32*)&Ks[t][d8 + 2] = kv.y;
        *(u32*)&Ks[t][d8 + 4] = kv.z;
        *(u32*)&Ks[t][d8 + 6] = kv.w;
        uint4 vv = *(const uint4*)&Vb[src];
        *(uint4*)&Vp[t][d8 >> 1] = vv;
    }
    if (tid < 128)      *(float4*)&gS[tid * 4] = *(const float4*)&g[tid * 4];
    else if (tid < 256) *(float4*)&beS[(tid - 128) * 4] = *(const float4*)&be[(tid - 128) * 4];
    {   // LN stats: 16 threads per row (32 rows)
        int r = tid >> 4, sub = tid & 15;
        const float* xr = Xb + (size_t)r * D + sub * 32;
        float sum = 0.f, ss = 0.f;
#pragma unroll
        for (int c = 0; c < 8; ++c) {
            float4 f = *(const float4*)&xr[c * 4];
            sum += f.x + f.y + f.z + f.w;
            ss  += f.x * f.x + f.y * f.y + f.z * f.z + f.w * f.w;
        }
#pragma unroll
        for (int o = 1; o < 16; o <<= 1) {
            sum += __shfl_xor(sum, o);
            ss  += __shfl_xor(ss, o);
        }
        if (sub == 0) {
            float mu  = sum * (1.f / D);
            float var = ss * (1.f / D) - mu * mu;
            muS[r] = mu;
            rsS[r] = rsqrtf(var + 1e-6f);
        }
    }
    __syncthreads();

    f4_t accQ = (f4_t){0.f, 0.f, 0.f, 0.f};
    for (int kc = 0; kc < 512; kc += 64) {
        writeLDS(kc);
        __syncthreads();
        if (kc < 448) { loadA(kc + 64); loadW(kc + 64); }
#pragma unroll
        for (int ks = 0; ks < 2; ++ks) {
            int ko = ks * 32 + quad * 8;
            bf8_t aq = *(const bf8_t*)&As[(w & 1) * 16 + m16][ko];
            bf8_t bq2 = *(const bf8_t*)&Wqs[(w >> 1) * 16 + m16][ko];
            accQ = __builtin_amdgcn_mfma_f32_16x16x32_bf16(aq, bq2, accQ, 0, 0, 0);
        }
        __syncthreads();
    }
    {
        int col = (w >> 1) * 16 + m16;
        float bqv = bq[h * 64 + col];
#pragma unroll
        for (int r = 0; r < 4; ++r)
            Qs[(w & 1) * 16 + quad * 4 + r][col] = f2bs(accQ[r] + bqv);
    }
    __syncthreads();

    int d2 = lane & 31, th = lane >> 5;
    bool pad0 = (mask_ids[b * S + lane] == 1);
    bool pad1 = (mask_ids[b * S + 64 + lane] == 1);

    for (int qi = 0; qi < 4; ++qi) {
        int qloc = w * 4 + qi;
        int qpos = qc * 32 + qloc;

        float s0 = 0.f, s1 = 0.f;
#pragma unroll
        for (int i = 0; i < 32; ++i) {
            u32 qu = *(const u32*)&Qs[qloc][2 * i];
            u32 k0 = *(const u32*)&Ks[lane][2 * i];
            u32 k1 = *(const u32*)&Ks[lane + 64][2 * i];
            float ql = blo(qu), qh = bhi(qu);
            s0 += ql * blo(k0) + qh * bhi(k0);
            s1 += ql * blo(k1) + qh * bhi(k1);
        }
        s0 *= 0.125f; s1 *= 0.125f;
        if (pad0) s0 = -1e30f;
        if (pad1) s1 = -1e30f;

        float mx = fmaxf(s0, s1);
#pragma unroll
        for (int off = 32; off > 0; off >>= 1) mx = fmaxf(mx, __shfl_xor(mx, off));
        float e0 = __expf(s0 - mx), e1 = __expf(s1 - mx);
        float l = e0 + e1;
#pragma unroll
        for (int off = 32; off > 0; off >>= 1) l += __shfl_xor(l, off);
        float inv = 1.f / l;
        es[w][lane]      = e0 * inv;
        es[w][lane + 64] = e1 * inv;

        float o0 = 0.f, o1 = 0.f;
#pragma unroll 8
        for (int i = 0; i < 64; ++i) {
            int t = th * 64 + i;
            float e = es[w][t];
            u32 vu = Vp[t][d2];
            o0 += e * blo(vu);
            o1 += e * bhi(vu);
        }
        o0 += __shfl_xor(o0, 32);
        o1 += __shfl_xor(o1, 32);
        if (th == 0) {
            u32 packed = ((u32)f2bs(o1) << 16) | f2bs(o0);
            *(u32*)&Ob[(size_t)(b * S + qpos) * D + h * DK + 2 * d2] = packed;
        }
    }
}

// ---------------------------------------------------------------------------
// Fused log-softmax: one block per row, 125 elements/thread in registers.
// ---------------------------------------------------------------------------
__global__ __launch_bounds__(256) void lsm_kernel(float* __restrict__ out)
{
    __shared__ float red[8];
    int row = blockIdx.x, tid = threadIdx.x;
    float* rp = out + (size_t)row * V;
    float v[125];
    float m = -1e30f;
#pragma unroll
    for (int i = 0; i < 125; ++i) {
        v[i] = rp[i * 256 + tid];
        m = fmaxf(m, v[i]);
    }
#pragma unroll
    for (int off = 32; off > 0; off >>= 1) m = fmaxf(m, __shfl_xor(m, off));
    int wv = tid >> 6;
    if ((tid & 63) == 0) red[wv] = m;
    __syncthreads();
    m = fmaxf(fmaxf(red[0], red[1]), fmaxf(red[2], red[3]));
    float l = 0.f;
#pragma unroll
    for (int i = 0; i < 125; ++i) l += __expf(v[i] - m);
#pragma unroll
    for (int off = 32; off > 0; off >>= 1) l += __shfl_xor(l, off);
    if ((tid & 63) == 0) red[4 + wv] = l;
    __syncthreads();
    l = (red[4] + red[5]) + (red[6] + red[7]);
    float c = m + logf(l);
#pragma unroll
    for (int i = 0; i < 125; ++i) rp[i * 256 + tid] = v[i] - c;
}

// ---------------------------------------------------------------------------
// Host orchestration
// ---------------------------------------------------------------------------
extern "C" void kernel_launch(void* const* d_in, const int* in_sizes, int n_in,
                              void* d_out, int out_size, void* d_ws, size_t ws_size,
                              hipStream_t stream)
{
    const int*   src        = (const int*)d_in[0];
    const int*   tgt        = (const int*)d_in[1];
    const float* tok_emb    = (const float*)d_in[2];
    const float* pos_emb    = (const float*)d_in[3];
    const float* enc_attn_w = (const float*)d_in[4];
    const float* enc_attn_b = (const float*)d_in[5];
    const float* enc_ffn_w1 = (const float*)d_in[6];
    const float* enc_ffn_b1 = (const float*)d_in[7];
    const float* enc_ffn_w2 = (const float*)d_in[8];
    const float* enc_ffn_b2 = (const float*)d_in[9];
    const float* enc_ln     = (const float*)d_in[10];
    const float* enc_fln    = (const float*)d_in[11];
    const float* dec_attn_w = (const float*)d_in[12];
    const float* dec_attn_b = (const float*)d_in[13];
    const float* dec_ffn_w1 = (const float*)d_in[14];
    const float* dec_ffn_b1 = (const float*)d_in[15];
    const float* dec_ffn_w2 = (const float*)d_in[16];
    const float* dec_ffn_b2 = (const float*)d_in[17];
    const float* dec_ln     = (const float*)d_in[18];
    const float* dec_fln    = (const float*)d_in[19];
    float* out = (float*)d_out;

    const size_t TOKD = (size_t)NTOK * D;
    const size_t DD   = (size_t)D * D;
    const size_t DF   = (size_t)D * FF;

    char* p = (char*)d_ws;
    auto carve = [&](size_t bytes) {
        void* r = (void*)p;
        p += (bytes + 255) & ~(size_t)255;
        return r;
    };
    u16* wtEA  = (u16*)carve(24 * DD * 2);
    u16* wtEF1 = (u16*)carve(6 * DF * 2);
    u16* wtEF2 = (u16*)carve(6 * DF * 2);
    u16* wtDA  = (u16*)carve(48 * DD * 2);
    u16* wtDF1 = (u16*)carve(6 * DF * 2);
    u16* wtDF2 = (u16*)carve(6 * DF * 2);
    u16* emb16 = (u16*)carve((size_t)V * D * 2);
    float* xe  = (float*)carve(TOKD * 4);
    float* xd  = (float*)carve(TOKD * 4);
    u16* h16   = (u16*)carve(TOKD * 2);
    u16* ao16  = (u16*)carve(TOKD * 2);
    u16* mem16 = (u16*)carve(TOKD * 2);
    u16* mid16 = (u16*)carve((size_t)NTOK * FF * 2);
    u16* kc16  = (u16*)carve(6 * TOKD * 2);
    u16* vc16  = (u16*)carve(6 * TOKD * 2);

    dim3 b256(256), b512(512), b64(64);
    dim3 gP  (8, 32, 1);
    dim3 gKV6(8, 32, 6);
    dim3 gF1 (32, 16, 1);
    dim3 gF2 (8, 32, 1);
    dim3 gGen(8064, 1, 1);
    dim3 gAttn(4, H, B);

    // ---- one-shot preprocessing (weights, emb16, embeddings) ----
    prep<<<61056, b256, 0, stream>>>(enc_attn_w, enc_ffn_w1, enc_ffn_w2,
                                     dec_attn_w, dec_ffn_w1, dec_ffn_w2,
                                     wtEA, wtEF1, wtEF2, wtDA, wtDF1, wtDF2,
                                     tok_emb, emb16, src, tgt, pos_emb, xe, xd);

    // ================= encoder =================
    for (int i = 0; i < NL; ++i) {
        const float* bb  = enc_attn_b + (size_t)i * 4 * D;
        const float* ln0 = enc_ln + (size_t)((i * 2 + 0) * 2) * D;
        const float* ln1 = enc_ln + (size_t)((i * 2 + 1) * 2) * D;

        fqa<<<gAttn, b512, 0, stream>>>(xe, ln0, ln0 + D, wtEA + (size_t)i * 4 * DD,
                                        bb, ao16, src, 0);
        gk<32, 128, 0><<<gP, b256, 0, stream>>>(ao16, nullptr, nullptr, nullptr,
            wtEA + (size_t)(i * 4 + 3) * DD, bb + 3 * D, xe, xe,
            512, 512, 0, 0, 0, 0, 0, 0);
        gk<64, 128, 1><<<gF1, b256, 0, stream>>>(nullptr, xe, ln1, ln1 + D,
            wtEF1 + (size_t)i * DF, enc_ffn_b1 + (size_t)i * FF, nullptr, mid16,
            512, 2048, 1, 1, 0, 0, 0, 0);
        gk<32, 128, 0><<<gF2, b256, 0, stream>>>(mid16, nullptr, nullptr, nullptr,
            wtEF2 + (size_t)i * DF, enc_ffn_b2 + (size_t)i * D, xe, xe,
            2048, 512, 0, 0, 0, 0, 0, 0);
    }
    ln_kernel<<<NTOK, b64, 0, stream>>>(xe, enc_fln, enc_fln + D, mem16);

    // cross-attn K,V for ALL 6 decoder layers: 2 batched launches
    gk<32, 128, 0><<<gKV6, b256, 0, stream>>>(mem16, nullptr, nullptr, nullptr,
        wtDA + 5 * DD, dec_attn_b + 5 * D, nullptr, kc16,
        512, 512, 0, 1, 0, (long)(8 * DD), (long)(8 * D), (long)TOKD);
    gk<32, 128, 0><<<gKV6, b256, 0, stream>>>(mem16, nullptr, nullptr, nullptr,
        wtDA + 6 * DD, dec_attn_b + 6 * D, nullptr, vc16,
        512, 512, 0, 1, 0, (long)(8 * DD), (long)(8 * D), (long)TOKD);

    // ================= decoder =================
    for (int i = 0; i < NL; ++i) {
        const float* bb  = dec_attn_b + (size_t)i * 8 * D;
        const u16*   wt  = wtDA + (size_t)i * 8 * DD;
        const float* ln0 = dec_ln + (size_t)((i * 3 + 0) * 2) * D;
        const float* ln1 = dec_ln + (size_t)((i * 3 + 1) * 2) * D;
        const float* ln2 = dec_ln + (size_t)((i * 3 + 2) * 2) * D;

        fqa<<<gAttn, b512, 0, stream>>>(xd, ln0, ln0 + D, wt, bb, ao16, tgt, 1);
        gk<32, 128, 0><<<gP, b256, 0, stream>>>(ao16, nullptr, nullptr, nullptr,
            wt + 3 * DD, bb + 3 * D, xd, xd,
            512, 512, 0, 0, 0, 0, 0, 0);

        fca<<<gAttn, b512, 0, stream>>>(xd, ln1, ln1 + D, wt + 4 * DD, bb + 4 * D,
                                        kc16 + (size_t)i * TOKD, vc16 + (size_t)i * TOKD,
                                        ao16, src);
        gk<32, 128, 0><<<gP, b256, 0, stream>>>(ao16, nullptr, nullptr, nullptr,
            wt + 7 * DD, bb + 7 * D, xd, xd,
            512, 512, 0, 0, 0, 0, 0, 0);

        gk<64, 128, 1><<<gF1, b256, 0, stream>>>(nullptr, xd, ln2, ln2 + D,
            wtDF1 + (size_t)i * DF, dec_ffn_b1 + (size_t)i * FF, nullptr, mid16,
            512, 2048, 1, 1, 0, 0, 0, 0);
        gk<32, 128, 0><<<gF2, b256, 0, stream>>>(mid16, nullptr, nullptr, nullptr,
            wtDF2 + (size_t)i * DF, dec_ffn_b2 + (size_t)i * D, xd, xd,
            2048, 512, 0, 0, 0, 0, 0, 0);
    }
    ln_kernel<<<NTOK, b64, 0, stream>>>(xd, dec_fln, dec_fln + D, h16);

    // ================= generator =================
    gk<64, 64, 0><<<gGen, b256, 0, stream>>>(h16, nullptr, nullptr, nullptr,
        emb16, nullptr, nullptr, out,
        512, V, 0, 0, 1, 0, 0, 0);
    lsm_kernel<<<NTOK, b256, 0, stream>>>(out);
}